// Round 7
// baseline (92135.016 us; speedup 1.0000x reference)
//
#include <hip/hip_runtime.h>
#include <hip/hip_bf16.h>
#include <stdint.h>
#include <stddef.h>

// ---------------------------------------------------------------------------
// LFADS forward on MI355X — round 6.
// R4/R5 post-mortem: agent-scope ATOMIC data loads don't coalesce (1 L3
// transaction per lane) -> 8x request amplification -> 35-90us/step latency
// wall. R1-R3 showed plain loads are cheap but release fences (buffer_wbl2)
// are not. This round:
//  - cross-WG WRITES: relaxed agent atomics (write-through, no wbl2)
//  - cross-WG READS: PLAIN coalesced loads + one acquire fence (buffer_inv
//    only) per barrier phase; L2 re-fills are shared by ~16 WGs/XCD
//  - barriers: 8-line spread posts + lane-parallel poll w/ shuffle-sum
//  - two independent sync groups (b-halves are independent recurrences)
// ---------------------------------------------------------------------------

#define B_    128
#define T_    1000
#define DIN_  64
#define E_    256
#define F_    64
#define H1_   80
#define DOUT_ 64
#define GEB   (E_*B_)
#define CLIPV 5.0f
#define LVMIN_ (-9.210340371976182f)

typedef unsigned short ushort_t;
typedef unsigned int uint_t;
typedef unsigned long long ull_t;

__device__ __forceinline__ float sigm_(float x) { return 1.0f/(1.0f + expf(-x)); }
__device__ __forceinline__ float bfu_(ushort_t u) { return __uint_as_float(((unsigned)u) << 16); }
__device__ __forceinline__ ushort_t bfbits_(float f) {
  __hip_bfloat16 h = __float2bfloat16(f);
  return *reinterpret_cast<ushort_t*>(&h);
}
__device__ __forceinline__ void vm_drain() { asm volatile("s_waitcnt vmcnt(0)" ::: "memory"); }
__device__ __forceinline__ void inv_() { __builtin_amdgcn_fence(__ATOMIC_ACQUIRE, "agent"); }

__device__ __forceinline__ void stc_f32(float* p, float v) {
  __hip_atomic_store(p, v, __ATOMIC_RELAXED, __HIP_MEMORY_SCOPE_AGENT);
}
__device__ __forceinline__ void stc_u32(uint_t* p, uint_t v) {
  __hip_atomic_store(p, v, __ATOMIC_RELAXED, __HIP_MEMORY_SCOPE_AGENT);
}
__device__ __forceinline__ void stc_u64(ull_t* p, ull_t v) {
  __hip_atomic_store(p, v, __ATOMIC_RELAXED, __HIP_MEMORY_SCOPE_AGENT);
}
__device__ __forceinline__ int ld_line(int* p) {
  return __hip_atomic_load(p, __ATOMIC_RELAXED, __HIP_MEMORY_SCOPE_AGENT);
}

// Control-line offsets (ints; one line = 16 ints = 64B)
#define LA(g,i) (((g)*32 + (i))*16)        // consumer c-posts, 8 lines/group
#define LB(g,i) (((g)*32 + 8 + (i))*16)    // consumer g-posts, 8 lines/group
#define LM(g,i) (((g)*32 + 16 + (i))*16)   // MLP posts, 2 lines/group
#define LF(s)   ((64 + (s))*16)            // ge ring flags, 128 lines
#define LE(e,i) ((192 + (e)*4 + (i))*16)   // encoder groups, 4 lines each

// Multi-line wait: lane i (i<16) loads ctl[loff], shuffle-sum, compare.
__device__ __forceinline__ void waitS_(int* ctl, int loff, int target,
                                       volatile int* s_go, int& alive) {
  if (!alive) return;
  __syncthreads();
  if ((threadIdx.x >> 6) == 0) {
    int guard = 0, ok = 1;
    for (;;) {
      int v = (loff >= 0) ? ld_line(ctl + loff) : 0;
      v += __shfl_down(v, 8); v += __shfl_down(v, 4);
      v += __shfl_down(v, 2); v += __shfl_down(v, 1);
      if (__shfl(v, 0) >= target) break;
      __builtin_amdgcn_s_sleep(2);
      if (++guard > 100000) { ok = 0; break; }
    }
    if ((threadIdx.x & 63) == 0) *s_go = ok;
  }
  __syncthreads();
  if (!*s_go) alive = 0;
  __syncthreads();
}

// Producer wait: lanes 0-7 = group0 A-lines, lanes 8-15 = group1 A-lines;
// require EACH group sum >= target (groups can skew arbitrarily).
__device__ __forceinline__ void waitP_(int* ctl, int loff, int target,
                                       volatile int* s_go, int& alive) {
  if (!alive) return;
  __syncthreads();
  if ((threadIdx.x >> 6) == 0) {
    int guard = 0, ok = 1;
    for (;;) {
      int v = (loff >= 0) ? ld_line(ctl + loff) : 0;
      v += __shfl_down(v, 4); v += __shfl_down(v, 2); v += __shfl_down(v, 1);
      const int m0 = __shfl(v, 0), m1 = __shfl(v, 8);
      if (m0 >= target && m1 >= target) break;
      __builtin_amdgcn_s_sleep(4);
      if (++guard > 100000) { ok = 0; break; }
    }
    if ((threadIdx.x & 63) == 0) *s_go = ok;
  }
  __syncthreads();
  if (!*s_go) alive = 0;
  __syncthreads();
}

// Single-location wait (ge ring flags).
__device__ __forceinline__ void wait1_(int* loc, int target,
                                       volatile int* s_go, int& alive) {
  if (!alive) return;
  __syncthreads();
  if (threadIdx.x == 0) {
    int guard = 0, ok = 1;
    while (ld_line(loc) < target) {
      __builtin_amdgcn_s_sleep(2);
      if (++guard > 100000) { ok = 0; break; }
    }
    *s_go = ok;
  }
  __syncthreads();
  if (!*s_go) alive = 0;
  __syncthreads();
}

// Drain own stores, then post +1 to a control line.
__device__ __forceinline__ void post_(int* ctl, int line_off) {
  vm_drain();
  __syncthreads();
  if (threadIdx.x == 0)
    __hip_atomic_fetch_add(ctl + line_off, 1, __ATOMIC_RELAXED, __HIP_MEMORY_SCOPE_AGENT);
}

// ------------------------- prep kernels ------------------------------------

// x[B][T][DIN] -> xT[T][DIN][B]
__global__ void k_transpose_x(const float* __restrict__ x, float* __restrict__ xT) {
  __shared__ float tile[64][65];
  const int t = blockIdx.x, bh = blockIdx.y;
  const int lane = threadIdx.x & 63, w = threadIdx.x >> 6;
  for (int i = 0; i < 16; ++i) {
    const int bl = w*16 + i;
    tile[bl][lane] = x[(size_t)(bh*64 + bl)*(T_*DIN_) + (size_t)t*DIN_ + lane];
  }
  __syncthreads();
  for (int i = 0; i < 16; ++i) {
    const int k = w*16 + i;
    xT[(size_t)t*(DIN_*B_) + (size_t)k*B_ + bh*64 + lane] = tile[lane][k];
  }
}

// eps_u[B][T][2] -> epsT[T][2][B]
__global__ void k_transpose_eps(const float* __restrict__ eps_u, float* __restrict__ epsT) {
  const int t = blockIdx.x;
  const int o = threadIdx.x >> 7, b = threadIdx.x & 127;
  epsT[(size_t)t*2*B_ + o*B_ + b] = eps_u[(size_t)b*(T_*2) + t*2 + o];
}

// M[768][E] = con_wih[:,512:576] @ fac_w ; Wfb[768] = con_wih[:,512:576] @ fac_b
__global__ void k_composite(const float* __restrict__ conwih, const float* __restrict__ facw,
                            const float* __restrict__ facb, float* __restrict__ M,
                            float* __restrict__ Wfb) {
  const int idx = blockIdx.x*256 + threadIdx.x;
  const int j = idx >> 8, k = idx & 255;
  float acc = 0.0f;
  for (int ff = 0; ff < F_; ++ff)
    acc += conwih[(size_t)j*576 + 512 + ff] * facw[(size_t)ff*E_ + k];
  M[(size_t)j*E_ + k] = acc;
  if (k == 0) {
    float s = 0.0f;
    for (int ff = 0; ff < F_; ++ff) s += conwih[(size_t)j*576 + 512 + ff] * facb[ff];
    Wfb[j] = s;
  }
}

// ------------------------- encoder -----------------------------------------

struct EncArgs {
  const float* xT;             // [T][DIN][B]
  const float* wih[4];
  const float* whh[4];
  const float* bih[4];
  const float* bhh[4];
  ull_t* hT;                   // [4][2][E/2][B] packed f32 pairs
  __hip_bfloat16* efS;         // [T][E][B]
  __hip_bfloat16* ebS;
  int* ctl;
};

__global__ __launch_bounds__(256, 1) void k_encoder(EncArgs a) {
  __shared__ float s_we[7680];
  __shared__ int s_goE;
  const int chain = blockIdx.x >> 6;
  const int rnk   = blockIdx.x & 63;
  const int jjg   = rnk >> 1;
  const int bg    = rnk & 1;
  const int lane  = threadIdx.x & 63;
  const int w     = threadIdx.x >> 6;
  const int b     = bg*64 + lane;
  const int e     = chain*2 + bg;

  const float* wih = a.wih[chain];
  const float* whh = a.whh[chain];
  const float* bih = a.bih[chain];
  const float* bhh = a.bhh[chain];
  ull_t* hTc = a.hT + (size_t)chain*GEB;
  const bool bwd = (chain >= 2);
  __hip_bfloat16* st = (chain == 1) ? a.efS : (chain == 3 ? a.ebS : nullptr);
  const int postL = LE(e, jjg & 3);
  const int waitL = (lane < 4) ? LE(e, lane) : -1;   // group has 4 lines

  for (int idx = threadIdx.x; idx < 7680; idx += 256) {
    const int jl = idx / 960, r = idx % 960;
    const int jj = jjg*8 + jl;
    float v;
    if (r < 192) { const int gate = r/64, c = r%64;
      v = wih[(size_t)(gate*E_ + jj)*DIN_ + c];
    } else { const int rh = r - 192; const int gate = rh/256, c = rh%256;
      v = whh[(size_t)(gate*E_ + jj)*E_ + c];
    }
    s_we[idx] = v;
  }
  __syncthreads();

  const int j0l = 2*w, j1l = 2*w + 1;
  const int j0 = jjg*8 + j0l, j1 = j0 + 1;

  const float brz0 = bih[j0] + bhh[j0];
  const float brz1 = bih[j1] + bhh[j1];
  const float bz0  = bih[E_+j0] + bhh[E_+j0];
  const float bz1  = bih[E_+j1] + bhh[E_+j1];
  const float bni0 = bih[2*E_+j0], bni1 = bih[2*E_+j1];
  const float bnh0 = bhh[2*E_+j0], bnh1 = bhh[2*E_+j1];

  const float4* wr0x = (const float4*)(s_we + j0l*960);
  const float4* wz0x = (const float4*)(s_we + j0l*960 + 64);
  const float4* wn0x = (const float4*)(s_we + j0l*960 + 128);
  const float4* wr0h = (const float4*)(s_we + j0l*960 + 192);
  const float4* wz0h = (const float4*)(s_we + j0l*960 + 448);
  const float4* wn0h = (const float4*)(s_we + j0l*960 + 704);
  const float4* wr1x = (const float4*)(s_we + j1l*960);
  const float4* wz1x = (const float4*)(s_we + j1l*960 + 64);
  const float4* wn1x = (const float4*)(s_we + j1l*960 + 128);
  const float4* wr1h = (const float4*)(s_we + j1l*960 + 192);
  const float4* wz1h = (const float4*)(s_we + j1l*960 + 448);
  const float4* wn1h = (const float4*)(s_we + j1l*960 + 704);

  int alive = 1;
  int p = 0;
  for (int t = 0; t < T_; ++t) {
    const int tt = bwd ? (T_-1-t) : t;
    const float* xp = a.xT + (size_t)tt*DIN_*B_ + b;
    const ull_t* hp = hTc + (size_t)p*(GEB/2) + b;
    float ar0=0,az0=0,an0=0,ah0=0, ar1=0,az1=0,an1=0,ah1=0;
    for (int k4 = 0; k4 < 16; ++k4) {
      const float x0 = xp[(4*k4+0)*B_], x1 = xp[(4*k4+1)*B_];
      const float x2 = xp[(4*k4+2)*B_], x3 = xp[(4*k4+3)*B_];
      float4 v;
      v = wr0x[k4]; ar0 += v.x*x0 + v.y*x1 + v.z*x2 + v.w*x3;
      v = wz0x[k4]; az0 += v.x*x0 + v.y*x1 + v.z*x2 + v.w*x3;
      v = wn0x[k4]; an0 += v.x*x0 + v.y*x1 + v.z*x2 + v.w*x3;
      v = wr1x[k4]; ar1 += v.x*x0 + v.y*x1 + v.z*x2 + v.w*x3;
      v = wz1x[k4]; az1 += v.x*x0 + v.y*x1 + v.z*x2 + v.w*x3;
      v = wn1x[k4]; an1 += v.x*x0 + v.y*x1 + v.z*x2 + v.w*x3;
    }
    for (int k4 = 0; k4 < 64; ++k4) {       // PLAIN coalesced reads (post-inv)
      const ull_t q0 = hp[(size_t)(2*k4+0)*B_];
      const ull_t q1 = hp[(size_t)(2*k4+1)*B_];
      const float h0 = __uint_as_float((unsigned)q0);
      const float h1 = __uint_as_float((unsigned)(q0 >> 32));
      const float h2 = __uint_as_float((unsigned)q1);
      const float h3 = __uint_as_float((unsigned)(q1 >> 32));
      float4 v;
      v = wr0h[k4]; ar0 += v.x*h0 + v.y*h1 + v.z*h2 + v.w*h3;
      v = wz0h[k4]; az0 += v.x*h0 + v.y*h1 + v.z*h2 + v.w*h3;
      v = wn0h[k4]; ah0 += v.x*h0 + v.y*h1 + v.z*h2 + v.w*h3;
      v = wr1h[k4]; ar1 += v.x*h0 + v.y*h1 + v.z*h2 + v.w*h3;
      v = wz1h[k4]; az1 += v.x*h0 + v.y*h1 + v.z*h2 + v.w*h3;
      v = wn1h[k4]; ah1 += v.x*h0 + v.y*h1 + v.z*h2 + v.w*h3;
    }
    const ull_t qp = hp[(size_t)(j0 >> 1)*B_];
    const float hprev0 = __uint_as_float((unsigned)qp);
    const float hprev1 = __uint_as_float((unsigned)(qp >> 32));
    const float r0 = sigm_(ar0 + brz0);
    const float z0 = sigm_(az0 + bz0);
    const float n0 = tanhf(an0 + bni0 + r0*(ah0 + bnh0));
    const float h0n = fminf((1.0f - z0)*n0 + z0*hprev0, CLIPV);
    const float r1 = sigm_(ar1 + brz1);
    const float z1 = sigm_(az1 + bz1);
    const float n1 = tanhf(an1 + bni1 + r1*(ah1 + bnh1));
    const float h1n = fminf((1.0f - z1)*n1 + z1*hprev1, CLIPV);
    ull_t* hq = hTc + (size_t)(p^1)*(GEB/2) + (size_t)(j0 >> 1)*B_ + b;
    stc_u64(hq, ((ull_t)__float_as_uint(h1n) << 32) | __float_as_uint(h0n));
    if (st) {   // archive: plain store (cross-kernel; dirty lines survive inv)
      st[(size_t)tt*GEB + (size_t)j0*B_ + b] = __float2bfloat16(h0n);
      st[(size_t)tt*GEB + (size_t)j1*B_ + b] = __float2bfloat16(h1n);
    }
    post_(a.ctl, postL);
    waitS_(a.ctl, waitL, 32*(t+1), &s_goE, alive);
    inv_();
    p ^= 1;
  }
}

// ------------------------- g0 sample ----------------------------------------

__global__ void k_g0(const ull_t* __restrict__ hT, const float* __restrict__ g0mw,
                     const float* __restrict__ g0mb, const float* __restrict__ g0vw,
                     const float* __restrict__ g0vb, const float* __restrict__ eps_g0,
                     float* __restrict__ ppx) {
  const int b = threadIdx.x & 127;
  const int half = threadIdx.x >> 7;
  const int kout = blockIdx.x*2 + half;
  const ull_t* hf = hT + b;               // chain0 (egf), buffer 0
  const ull_t* hb = hT + 2*GEB + b;       // chain2 (egb), buffer 0
  const float* mrow = g0mw + (size_t)kout*512;
  const float* vrow = g0vw + (size_t)kout*512;
  float dm = 0.0f, dv = 0.0f;
  for (int p = 0; p < 128; ++p) {
    const ull_t q = hf[(size_t)p*B_];
    const float h0 = __uint_as_float((unsigned)q);
    const float h1 = __uint_as_float((unsigned)(q >> 32));
    dm += mrow[2*p]*h0 + mrow[2*p+1]*h1;
    dv += vrow[2*p]*h0 + vrow[2*p+1]*h1;
  }
  for (int p = 0; p < 128; ++p) {
    const ull_t q = hb[(size_t)p*B_];
    const float h0 = __uint_as_float((unsigned)q);
    const float h1 = __uint_as_float((unsigned)(q >> 32));
    dm += mrow[256+2*p]*h0 + mrow[256+2*p+1]*h1;
    dv += vrow[256+2*p]*h0 + vrow[256+2*p+1]*h1;
  }
  const float lv = fmaxf(dv + g0vb[kout], LVMIN_);
  const float g = eps_g0[(size_t)b*E_ + kout]*expf(0.5f*lv) + dm + g0mb[kout];
  ppx[((size_t)kout*B_ + b)*2] = g;
}

// ------------------------- generator (3 roles) -------------------------------

struct GenAll {
  const float* M; const float* conwhh; const float* genwhh;
  const float* conbih; const float* conbhh; const float* Wfb;
  const float* genwih; const float* genbih; const float* genbhh;
  const float* umw; const float* umb; const float* uvw; const float* uvb;
  const float* epsT;          // [T][2][B]
  const float* conwih;        // [768][576]
  const __hip_bfloat16* efS;  // [T][E][B]
  const __hip_bfloat16* ebS;
  uint_t* ge;                 // ring [128][768][B] bf16
  ull_t* PP;                  // [2][E][B] packed (g,c) f32 pairs
  const float* facw; const float* facb;
  const float* f1w; const float* f1b;
  const float* clw; const float* clb;
  float* out;                 // [B][T][DOUT]
  int* ctl;
};

__global__ __launch_bounds__(256, 1) void k_generator(GenAll a) {
  __shared__ __align__(16) unsigned char s_raw[60416];
  const int lane = threadIdx.x & 63;
  const int w = threadIdx.x >> 6;

  if (blockIdx.x < 128) {
    // ======================= consumer =======================
    float* s_w   = (float*)s_raw;              // 4*2304 f32 = 36864 B
    float* s_uwT = (float*)(s_raw + 36864);    // [k][4]     = 4096 B
    float* s_up  = (float*)(s_raw + 40960);    // [4][256]   = 4096 B
    volatile int* s_go = (volatile int*)(s_raw + 45056);
    const int jjgq = blockIdx.x >> 1;
    const int g  = blockIdx.x & 1;             // b-half = sync group
    const int b  = g*64 + lane;

    const int postA = LA(g, jjgq & 7);
    const int postB = LB(g, jjgq & 7);
    const int waitStartL = (lane < 8) ? LB(g, lane)
                        : (lane < 10) ? LM(g, lane - 8) : -1;   // B(8)+M(2)
    const int waitMidL   = (lane < 8) ? LA(g, lane) : -1;

    for (int idx = threadIdx.x; idx < 9216; idx += 256) {
      const int jl = idx / 2304, r = idx % 2304;
      const int jj = jjgq*4 + jl;
      const int sec = r / 768, rr = r % 768, gate = rr >> 8, c = rr & 255;
      const float* src = (sec == 0) ? a.M : (sec == 1 ? a.conwhh : a.genwhh);
      s_w[idx] = src[(size_t)(gate*E_ + jj)*E_ + c];
    }
    for (int idx = threadIdx.x; idx < 1024; idx += 256) {
      const int k = idx >> 2, q = idx & 3;
      s_uwT[idx] = (q < 2) ? a.umw[q*E_ + k] : a.uvw[(q-2)*E_ + k];
    }
    __syncthreads();

    int j = jjgq*4 + w;
    j = __builtin_amdgcn_readfirstlane(j);
    const float* base = s_w + w*2304;
    const float4* Mr  = (const float4*)(base);
    const float4* Mz  = (const float4*)(base + 256);
    const float4* Mn  = (const float4*)(base + 512);
    const float4* Whr = (const float4*)(base + 768);
    const float4* Whz = (const float4*)(base + 1024);
    const float4* Whn = (const float4*)(base + 1280);
    const float4* Gwr = (const float4*)(base + 1536);
    const float4* Gwz = (const float4*)(base + 1792);
    const float4* Gwn = (const float4*)(base + 2048);

    const float brz_c = a.conbih[j] + a.conbhh[j] + a.Wfb[j];
    const float bz_c  = a.conbih[E_+j] + a.conbhh[E_+j] + a.Wfb[E_+j];
    const float bni_c = a.conbih[2*E_+j] + a.Wfb[2*E_+j];
    const float bnh_c = a.conbhh[2*E_+j];
    const float gur0 = a.genwih[j*2],        gur1 = a.genwih[j*2+1];
    const float guz0 = a.genwih[(E_+j)*2],   guz1 = a.genwih[(E_+j)*2+1];
    const float gun0 = a.genwih[(2*E_+j)*2], gun1 = a.genwih[(2*E_+j)*2+1];
    const float brz_g = a.genbih[j] + a.genbhh[j];
    const float bz_g  = a.genbih[E_+j] + a.genbhh[E_+j];
    const float bni_g = a.genbih[2*E_+j];
    const float bnh_g = a.genbhh[2*E_+j];
    const float umb0 = a.umb[0], umb1 = a.umb[1];
    const float uvb0 = a.uvb[0], uvb1 = a.uvb[1];

    int alive = 1;
    for (int t = 0; t < T_; ++t) {
      // start: all g_{t-1} posted + MLP snapshot t-1 done (combined-sum, sound)
      waitS_(a.ctl, waitStartL, 80*t, s_go, alive);
      inv_();
      const ull_t* ppb = a.PP + (size_t)(t&1)*GEB + b;
      ull_t* ppn = a.PP + (size_t)((t+1)&1)*GEB;
      const ull_t pv = ppb[(size_t)j*B_];
      const float gprev = __uint_as_float((unsigned)pv);
      const float cprev = __uint_as_float((unsigned)(pv >> 32));
      float ar=0,az=0,an=0,ah=0,gr=0,gz=0,gh=0;
      for (int k4 = 0; k4 < 64; ++k4) {     // PLAIN coalesced packed reads
        const ull_t v0 = ppb[(4*k4+0)*B_];
        const ull_t v1 = ppb[(4*k4+1)*B_];
        const ull_t v2 = ppb[(4*k4+2)*B_];
        const ull_t v3 = ppb[(4*k4+3)*B_];
        const float g0 = __uint_as_float((unsigned)v0), c0 = __uint_as_float((unsigned)(v0>>32));
        const float g1 = __uint_as_float((unsigned)v1), c1 = __uint_as_float((unsigned)(v1>>32));
        const float g2 = __uint_as_float((unsigned)v2), c2 = __uint_as_float((unsigned)(v2>>32));
        const float g3 = __uint_as_float((unsigned)v3), c3 = __uint_as_float((unsigned)(v3>>32));
        float4 v;
        v = Mr[k4];  ar += v.x*g0 + v.y*g1 + v.z*g2 + v.w*g3;
        v = Mz[k4];  az += v.x*g0 + v.y*g1 + v.z*g2 + v.w*g3;
        v = Mn[k4];  an += v.x*g0 + v.y*g1 + v.z*g2 + v.w*g3;
        v = Gwr[k4]; gr += v.x*g0 + v.y*g1 + v.z*g2 + v.w*g3;
        v = Gwz[k4]; gz += v.x*g0 + v.y*g1 + v.z*g2 + v.w*g3;
        v = Gwn[k4]; gh += v.x*g0 + v.y*g1 + v.z*g2 + v.w*g3;
        v = Whr[k4]; ar += v.x*c0 + v.y*c1 + v.z*c2 + v.w*c3;
        v = Whz[k4]; az += v.x*c0 + v.y*c1 + v.z*c2 + v.w*c3;
        v = Whn[k4]; ah += v.x*c0 + v.y*c1 + v.z*c2 + v.w*c3;
      }
      // ge[t] flag, then PLAIN bf16 reads (lines untouched since >many invs)
      wait1_(a.ctl + LF(t & 127), 48*((t >> 7) + 1), s_go, alive);
      {
        const ushort_t* gep = (const ushort_t*)a.ge + (size_t)(t & 127)*(768*B_) + b;
        ar += bfu_(gep[(size_t)j*B_]);
        az += bfu_(gep[(size_t)(E_+j)*B_]);
        an += bfu_(gep[(size_t)(2*E_+j)*B_]);
      }
      const float r = sigm_(ar + brz_c);
      const float z = sigm_(az + bz_c);
      const float n = tanhf(an + bni_c + r*(ah + bnh_c));
      const float cn = fminf((1.0f - z)*n + z*cprev, CLIPV);
      stc_f32((float*)(ppn + (size_t)j*B_ + b) + 1, cn);    // .y = c
      post_(a.ctl, postA);
      waitS_(a.ctl, waitMidL, 64*(t+1), s_go, alive);
      inv_();

      // ---- u partials over this wave's k-quarter of fresh c (plain) ----
      {
        const float* cq = (const float*)(ppn + b);
        float p0=0,p1=0,p2=0,p3=0;
        for (int kk = 0; kk < 64; ++kk) {
          const int k = w*64 + kk;
          const float cv = cq[(size_t)k*B_*2 + 1];
          const float4 uw = *(const float4*)(s_uwT + k*4);
          p0 += uw.x*cv; p1 += uw.y*cv; p2 += uw.z*cv; p3 += uw.w*cv;
        }
        s_up[0*256 + threadIdx.x] = p0;
        s_up[1*256 + threadIdx.x] = p1;
        s_up[2*256 + threadIdx.x] = p2;
        s_up[3*256 + threadIdx.x] = p3;
      }
      __syncthreads();
      const float m0 = s_up[lane] + s_up[64+lane] + s_up[128+lane] + s_up[192+lane] + umb0;
      const float m1 = s_up[256+lane] + s_up[320+lane] + s_up[384+lane] + s_up[448+lane] + umb1;
      const float lv0 = fmaxf(s_up[512+lane] + s_up[576+lane] + s_up[640+lane] + s_up[704+lane] + uvb0, LVMIN_);
      const float lv1 = fmaxf(s_up[768+lane] + s_up[832+lane] + s_up[896+lane] + s_up[960+lane] + uvb1, LVMIN_);
      __syncthreads();
      const float eps0 = a.epsT[(size_t)t*256 + b];
      const float eps1 = a.epsT[(size_t)t*256 + 128 + b];
      const float u0 = eps0*expf(0.5f*lv0) + m0;
      const float u1 = eps1*expf(0.5f*lv1) + m1;

      const float rg = sigm_(gr + gur0*u0 + gur1*u1 + brz_g);
      const float zg = sigm_(gz + guz0*u0 + guz1*u1 + bz_g);
      const float ng = tanhf(gun0*u0 + gun1*u1 + bni_g + rg*(gh + bnh_g));
      const float gn = fminf((1.0f - zg)*ng + zg*gprev, CLIPV);
      stc_f32((float*)(ppn + (size_t)j*B_ + b), gn);        // .x = g
      post_(a.ctl, postB);
    }
  } else if (blockIdx.x < 224) {
    // ======================= producer =======================
    float* s_wp = (float*)s_raw;                   // [512][16] f32 = 32768 B
    volatile int* s_go = (volatile int*)(s_raw + 32768);
    const int pid = blockIdx.x - 128;
    const int tile = pid % 48, phase = pid / 48;
    const int r0 = tile*16;
    const int waitL = (lane < 8) ? LA(0, lane)
                    : (lane < 16) ? LA(1, lane - 8) : -1;
    for (int idx = threadIdx.x; idx < 8192; idx += 256) {
      const int k = idx >> 4, rl = idx & 15;
      s_wp[idx] = a.conwih[(size_t)(r0 + rl)*576 + k];
    }
    __syncthreads();
    const int rl0 = w*4;       // 4 rows per wave, all 128 b (paired in u32)
    int alive = 1;
    for (int t = phase; t < T_; t += 2) {
      if (t >= 128)   // ring guard: EACH group's c-posts past step t-128
        waitP_(a.ctl, waitL, 64*(t - 127), s_go, alive);
      float a0l=0,a0h=0,a1l=0,a1h=0,a2l=0,a2h=0,a3l=0,a3h=0;
      const uint_t* efp = (const uint_t*)a.efS + (((size_t)t*GEB) >> 1) + lane;
      const uint_t* ebp = (const uint_t*)a.ebS + (((size_t)t*GEB) >> 1) + lane;
      for (int k = 0; k < 256; ++k) {
        const float4 wv = *(const float4*)(s_wp + k*16 + rl0);
        const uint_t u = efp[(size_t)k*(B_/2)];
        const float el = bfu_((ushort_t)u), eh = bfu_((ushort_t)(u >> 16));
        a0l += wv.x*el; a0h += wv.x*eh; a1l += wv.y*el; a1h += wv.y*eh;
        a2l += wv.z*el; a2h += wv.z*eh; a3l += wv.w*el; a3h += wv.w*eh;
      }
      for (int k = 0; k < 256; ++k) {
        const float4 wv = *(const float4*)(s_wp + (256+k)*16 + rl0);
        const uint_t u = ebp[(size_t)k*(B_/2)];
        const float el = bfu_((ushort_t)u), eh = bfu_((ushort_t)(u >> 16));
        a0l += wv.x*el; a0h += wv.x*eh; a1l += wv.y*el; a1h += wv.y*eh;
        a2l += wv.z*el; a2h += wv.z*eh; a3l += wv.w*el; a3h += wv.w*eh;
      }
      uint_t* gesl = a.ge + (((size_t)(t & 127)*(768*B_)) >> 1) + (size_t)(r0 + rl0)*(B_/2) + lane;
      stc_u32(gesl + 0*(B_/2), ((uint_t)bfbits_(a0h) << 16) | bfbits_(a0l));
      stc_u32(gesl + 1*(B_/2), ((uint_t)bfbits_(a1h) << 16) | bfbits_(a1l));
      stc_u32(gesl + 2*(B_/2), ((uint_t)bfbits_(a2h) << 16) | bfbits_(a2l));
      stc_u32(gesl + 3*(B_/2), ((uint_t)bfbits_(a3h) << 16) | bfbits_(a3l));
      vm_drain();
      __syncthreads();
      if (threadIdx.x == 0)
        __hip_atomic_fetch_add(a.ctl + LF(t & 127), 1, __ATOMIC_RELAXED, __HIP_MEMORY_SCOPE_AGENT);
    }
  } else {
    // ======================= output MLP =======================
    __hip_bfloat16* s_fw  = (__hip_bfloat16*)s_raw;              // [256][64]
    __hip_bfloat16* s_f1T = (__hip_bfloat16*)(s_raw + 32768);    // [64][80]
    __hip_bfloat16* s_clT = (__hip_bfloat16*)(s_raw + 43008);    // [80][64]
    float* s_g  = (float*)(s_raw + 53248);                       // [4][256]
    float* s_f  = (float*)(s_raw + 57344);                       // [4][64]
    float* s_h1 = (float*)(s_raw + 58368);                       // [4][80]
    volatile int* s_go = (volatile int*)(s_raw + 59648);
    for (int idx = threadIdx.x; idx < 16384; idx += 256) {
      const int k = idx >> 6, fd = idx & 63;
      s_fw[idx] = __float2bfloat16(a.facw[(size_t)fd*E_ + k]);
    }
    for (int idx = threadIdx.x; idx < 5120; idx += 256) {
      const int kf = idx / H1_, hd = idx % H1_;
      s_f1T[idx] = __float2bfloat16(a.f1w[(size_t)hd*64 + kf]);
    }
    for (int idx = threadIdx.x; idx < 5120; idx += 256) {
      const int kh = idx >> 6, od = idx & 63;
      s_clT[idx] = __float2bfloat16(a.clw[(size_t)od*H1_ + kh]);
    }
    __syncthreads();
    const int oid = blockIdx.x - 224;
    const int g = oid & 1;
    const int idxm = oid >> 1;           // 0..15
    int bw = g*64 + idxm*4 + w;
    bw = __builtin_amdgcn_readfirstlane(bw);
    const int postM = LM(g, idxm & 1);
    const int waitL = (lane < 8) ? LB(g, lane)
                    : (lane < 10) ? LM(g, lane - 8) : -1;
    const float facb_l = a.facb[lane];
    const float f1b_a  = a.f1b[lane];
    const float f1b_b  = (lane < 16) ? a.f1b[64 + lane] : 0.0f;
    const float clb_l  = a.clb[lane];
    int alive = 1;
    for (int t = 0; t <= T_; ++t) {
      waitS_(a.ctl, waitL, 80*t, s_go, alive);
      inv_();
      if (t > 0) {
        // snapshot g_{t-1} (PP[t&1].x) into LDS, THEN release consumers
        const float* ppx = (const float*)(a.PP + (size_t)(t&1)*GEB);
        #pragma unroll
        for (int i = 0; i < 4; ++i) {
          const int k = lane + 64*i;
          s_g[w*256 + k] = ppx[((size_t)k*B_ + bw)*2];
        }
      }
      vm_drain();
      __syncthreads();
      if (threadIdx.x == 0)
        __hip_atomic_fetch_add(a.ctl + postM, 1, __ATOMIC_RELAXED, __HIP_MEMORY_SCOPE_AGENT);
      if (t > 0) {
        const int tt = t - 1;
        float f = facb_l;
        for (int k = 0; k < 256; ++k)
          f += __bfloat162float(s_fw[k*64 + lane]) * s_g[w*256 + k];
        s_f[w*64 + lane] = f;
        __syncthreads();
        float h1a = f1b_a, h1b = f1b_b;
        for (int kf = 0; kf < 64; ++kf) {
          const float fv = s_f[w*64 + kf];
          h1a += __bfloat162float(s_f1T[kf*H1_ + lane]) * fv;
          if (lane < 16) h1b += __bfloat162float(s_f1T[kf*H1_ + 64 + lane]) * fv;
        }
        s_h1[w*H1_ + lane] = fmaxf(h1a, 0.0f);
        if (lane < 16) s_h1[w*H1_ + 64 + lane] = fmaxf(h1b, 0.0f);
        __syncthreads();
        float o = clb_l;
        for (int kh = 0; kh < H1_; ++kh)
          o += __bfloat162float(s_clT[kh*64 + lane]) * s_h1[w*H1_ + kh];
        a.out[((size_t)bw*T_ + tt)*DOUT_ + lane] = o;   // plain (kernel-local)
        __syncthreads();
      }
    }
  }
}

// ------------------------- host launcher ------------------------------------

extern "C" void kernel_launch(void* const* d_in, const int* in_sizes, int n_in,
                              void* d_out, int out_size, void* d_ws, size_t ws_size,
                              hipStream_t stream) {
  const float* x      = (const float*)d_in[0];
  const float* eps_g0 = (const float*)d_in[1];
  const float* eps_u  = (const float*)d_in[2];
  const float* egf_wih = (const float*)d_in[3],  *egf_whh = (const float*)d_in[4];
  const float* egf_bih = (const float*)d_in[5],  *egf_bhh = (const float*)d_in[6];
  const float* egb_wih = (const float*)d_in[7],  *egb_whh = (const float*)d_in[8];
  const float* egb_bih = (const float*)d_in[9],  *egb_bhh = (const float*)d_in[10];
  const float* ecf_wih = (const float*)d_in[11], *ecf_whh = (const float*)d_in[12];
  const float* ecf_bih = (const float*)d_in[13], *ecf_bhh = (const float*)d_in[14];
  const float* ecb_wih = (const float*)d_in[15], *ecb_whh = (const float*)d_in[16];
  const float* ecb_bih = (const float*)d_in[17], *ecb_bhh = (const float*)d_in[18];
  const float* con_wih = (const float*)d_in[19], *con_whh = (const float*)d_in[20];
  const float* con_bih = (const float*)d_in[21], *con_bhh = (const float*)d_in[22];
  const float* gen_wih = (const float*)d_in[23], *gen_whh = (const float*)d_in[24];
  const float* gen_bih = (const float*)d_in[25], *gen_bhh = (const float*)d_in[26];
  const float* g0m_w = (const float*)d_in[27], *g0m_b = (const float*)d_in[28];
  const float* g0v_w = (const float*)d_in[29], *g0v_b = (const float*)d_in[30];
  const float* um_w = (const float*)d_in[31], *um_b = (const float*)d_in[32];
  const float* uv_w = (const float*)d_in[33], *uv_b = (const float*)d_in[34];
  const float* fac_w = (const float*)d_in[35], *fac_b = (const float*)d_in[36];
  const float* f1_w = (const float*)d_in[37], *f1_b = (const float*)d_in[38];
  const float* cl_w = (const float*)d_in[39], *cl_b = (const float*)d_in[40];
  float* out = (float*)d_out;
  (void)ws_size; (void)in_sizes; (void)n_in; (void)out_size;

  // Workspace layout — total 167,262,208 B <= proven 167,297,024 B.
  char* ws = (char*)d_ws;
  const size_t o_xT   = 0;             // f32 [T][DIN][B]        32,768,000
  const size_t o_ge   = 0;             // bf16 [128][768][B]     25,165,824 (alias, xT dead)
  const size_t o_efS  = 32768000ul;    // bf16 [T][E][B]         65,536,000
  const size_t o_ebS  = 98304000ul;    //                        65,536,000
  const size_t o_epsT = 163840000ul;   // f32 [T][2][B]           1,024,000
  const size_t o_M    = 164864000ul;   // f32 [768][E]              786,432
  const size_t o_Wfb  = 165650432ul;   // f32 [768]                   4,096
  const size_t o_hT   = 165654528ul;   // ull [4][2][E/2][B]      1,048,576
  const size_t o_PP   = 166703104ul;   // ull [2][E][B]             524,288
  const size_t o_ctl  = 167227392ul;   // control lines              34,816
  const size_t o_end  = 167262208ul;

  float* xT = (float*)(ws + o_xT);
  uint_t* ge = (uint_t*)(ws + o_ge);
  __hip_bfloat16* efS = (__hip_bfloat16*)(ws + o_efS);
  __hip_bfloat16* ebS = (__hip_bfloat16*)(ws + o_ebS);
  float* epsT = (float*)(ws + o_epsT);
  float* M = (float*)(ws + o_M);
  float* Wfb = (float*)(ws + o_Wfb);
  ull_t* hT = (ull_t*)(ws + o_hT);
  ull_t* PP = (ull_t*)(ws + o_PP);
  int* ctl = (int*)(ws + o_ctl);

  // zero the ENTIRE state+control region (hT, PP, all control lines)
  hipMemsetAsync(ws + o_hT, 0, o_end - o_hT, stream);

  k_transpose_x<<<dim3(T_, 2), 256, 0, stream>>>(x, xT);
  k_transpose_eps<<<T_, 256, 0, stream>>>(eps_u, epsT);
  k_composite<<<768, 256, 0, stream>>>(con_wih, fac_w, fac_b, M, Wfb);

  EncArgs ea;
  ea.xT = xT;
  ea.wih[0] = egf_wih; ea.whh[0] = egf_whh; ea.bih[0] = egf_bih; ea.bhh[0] = egf_bhh;
  ea.wih[1] = ecf_wih; ea.whh[1] = ecf_whh; ea.bih[1] = ecf_bih; ea.bhh[1] = ecf_bhh;
  ea.wih[2] = egb_wih; ea.whh[2] = egb_whh; ea.bih[2] = egb_bih; ea.bhh[2] = egb_bhh;
  ea.wih[3] = ecb_wih; ea.whh[3] = ecb_whh; ea.bih[3] = ecb_bih; ea.bhh[3] = ecb_bhh;
  ea.hT = hT; ea.efS = efS; ea.ebS = ebS; ea.ctl = ctl;
  k_encoder<<<256, 256, 0, stream>>>(ea);

  k_g0<<<128, 256, 0, stream>>>(hT, g0m_w, g0m_b, g0v_w, g0v_b, eps_g0, (float*)PP);

  GenAll ga;
  ga.M = M; ga.conwhh = con_whh; ga.genwhh = gen_whh;
  ga.conbih = con_bih; ga.conbhh = con_bhh; ga.Wfb = Wfb;
  ga.genwih = gen_wih; ga.genbih = gen_bih; ga.genbhh = gen_bhh;
  ga.umw = um_w; ga.umb = um_b; ga.uvw = uv_w; ga.uvb = uv_b;
  ga.epsT = epsT; ga.conwih = con_wih;
  ga.efS = efS; ga.ebS = ebS; ga.ge = ge; ga.PP = PP;
  ga.facw = fac_w; ga.facb = fac_b;
  ga.f1w = f1_w; ga.f1b = f1_b; ga.clw = cl_w; ga.clb = cl_b;
  ga.out = out;
  ga.ctl = ctl;
  k_generator<<<256, 256, 0, stream>>>(ga);
}

// Round 8
// 53118.427 us; speedup vs baseline: 1.7345x; 1.7345x over previous
//
#include <hip/hip_runtime.h>
#include <hip/hip_bf16.h>
#include <stdint.h>
#include <stddef.h>

// ---------------------------------------------------------------------------
// LFADS forward on MI355X — round 7.
// R0-R6 post-mortem: every sync protocol costs 30-86us/step while ISA-level
// models predict 2-4us; VALUBusy 8-13% throughout. Hypothesis: clock
// throttling — all variants are >90% idle (s_sleep / barrier-blocked), DPM
// drops fclk ~5x. This round = R4 (measured best, 57.5ms) plus:
//  - busy-wait with v_fmac ballast (no s_sleep): wave0 polls L3, waves 1-3
//    spin on an LDS flag, ALL spinners burn FMAs to keep VALUBusy high
//  - MLP on a 4-deep PP ring (lag-tolerant, off the critical path)
//  - per-half 64-slot sync groups, monotonic store posts (no RMW contention)
// ---------------------------------------------------------------------------

#define B_    128
#define T_    1000
#define DIN_  64
#define E_    256
#define F_    64
#define H1_   80
#define DOUT_ 64
#define GEB   (E_*B_)
#define CLIPV 5.0f
#define LVMIN_ (-9.210340371976182f)

typedef unsigned short ushort_t;
typedef unsigned int uint_t;
typedef unsigned long long ull_t;

// control line indices (line = 16 ints = 64B)
#define CS_LINE(g,i)  ((g)*64 + (i))          // consumer slots, 64 per half
#define MS_LINE(g,i)  (128 + (g)*16 + (i))    // MLP slots, 16 per half
#define LF_LINE(s)    (160 + (s))             // ge ring flags, 128
#define ES_LINE(c,i)  (288 + (c)*64 + (i))    // encoder slots, 64 per chain

__device__ __forceinline__ float sigm_(float x) { return 1.0f/(1.0f + expf(-x)); }
__device__ __forceinline__ float bfu_(ushort_t u) { return __uint_as_float(((unsigned)u) << 16); }
__device__ __forceinline__ ushort_t bfbits_(float f) {
  __hip_bfloat16 h = __float2bfloat16(f);
  return *reinterpret_cast<ushort_t*>(&h);
}
__device__ __forceinline__ void vm_drain() { asm volatile("s_waitcnt vmcnt(0)" ::: "memory"); }

__device__ __forceinline__ float ldc_f32(const float* p) {
  return __hip_atomic_load(p, __ATOMIC_RELAXED, __HIP_MEMORY_SCOPE_AGENT);
}
__device__ __forceinline__ void stc_f32(float* p, float v) {
  __hip_atomic_store(p, v, __ATOMIC_RELAXED, __HIP_MEMORY_SCOPE_AGENT);
}
__device__ __forceinline__ uint_t ldc_u32(const uint_t* p) {
  return __hip_atomic_load(p, __ATOMIC_RELAXED, __HIP_MEMORY_SCOPE_AGENT);
}
__device__ __forceinline__ void stc_u32(uint_t* p, uint_t v) {
  __hip_atomic_store(p, v, __ATOMIC_RELAXED, __HIP_MEMORY_SCOPE_AGENT);
}
__device__ __forceinline__ ull_t ldc_u64(const ull_t* p) {
  return __hip_atomic_load(p, __ATOMIC_RELAXED, __HIP_MEMORY_SCOPE_AGENT);
}
__device__ __forceinline__ int ld_line(int* p) {
  return __hip_atomic_load(p, __ATOMIC_RELAXED, __HIP_MEMORY_SCOPE_AGENT);
}

// Anti-downclock ballast: ~48 dependent FMAs keep the SIMD issuing while we
// wait. asm volatile so it cannot be optimized away.
__device__ __forceinline__ void ballast_() {
  float z = 1.0001f;
  #pragma unroll
  for (int i = 0; i < 48; ++i)
    asm volatile("v_fmac_f32 %0, %0, %0" : "+v"(z));
}

// Scaffold: wave0 evaluates cond() (must return wave-uniform 0/1); waves 1-3
// spin on LDS go flag. All spinners run ballast. s_alive: sticky failsafe.
template <typename F>
__device__ __forceinline__ void waitT_(F cond, volatile int* s_go,
                                       volatile int* s_alive) {
  __syncthreads();
  if (*s_alive && threadIdx.x == 0) *s_go = 0;
  __syncthreads();
  if (!*s_alive) return;
  if (threadIdx.x < 64) {
    int guard = 0;
    for (;;) {
      if (cond()) break;
      ballast_();
      if (++guard > 50000) { if (threadIdx.x == 0) *s_alive = 0; break; }
    }
    if (threadIdx.x == 0) *s_go = 1;
  }
  while (!*s_go) ballast_();
  __syncthreads();
}

__device__ __forceinline__ int wave_min_ok(int v) {
  v = min(v, __shfl_xor(v, 32)); v = min(v, __shfl_xor(v, 16));
  v = min(v, __shfl_xor(v, 8));  v = min(v, __shfl_xor(v, 4));
  v = min(v, __shfl_xor(v, 2));  v = min(v, __shfl_xor(v, 1));
  return v >= 0;
}

// Drain own global stores, then post value / increment to a control line.
__device__ __forceinline__ void postS_(int* ctl, int line, int val) {
  vm_drain();
  __syncthreads();
  if (threadIdx.x == 0)
    __hip_atomic_store(ctl + line*16, val, __ATOMIC_RELAXED, __HIP_MEMORY_SCOPE_AGENT);
}
__device__ __forceinline__ void postF_(int* ctl, int line) {
  vm_drain();
  __syncthreads();
  if (threadIdx.x == 0)
    __hip_atomic_fetch_add(ctl + line*16, 1, __ATOMIC_RELAXED, __HIP_MEMORY_SCOPE_AGENT);
}

// ------------------------- prep kernels ------------------------------------

// x[B][T][DIN] -> xT[T][DIN][B]
__global__ void k_transpose_x(const float* __restrict__ x, float* __restrict__ xT) {
  __shared__ float tile[64][65];
  const int t = blockIdx.x, bh = blockIdx.y;
  const int lane = threadIdx.x & 63, w = threadIdx.x >> 6;
  for (int i = 0; i < 16; ++i) {
    const int bl = w*16 + i;
    tile[bl][lane] = x[(size_t)(bh*64 + bl)*(T_*DIN_) + (size_t)t*DIN_ + lane];
  }
  __syncthreads();
  for (int i = 0; i < 16; ++i) {
    const int k = w*16 + i;
    xT[(size_t)t*(DIN_*B_) + (size_t)k*B_ + bh*64 + lane] = tile[lane][k];
  }
}

// eps_u[B][T][2] -> epsT[T][2][B]
__global__ void k_transpose_eps(const float* __restrict__ eps_u, float* __restrict__ epsT) {
  const int t = blockIdx.x;
  const int o = threadIdx.x >> 7, b = threadIdx.x & 127;
  epsT[(size_t)t*2*B_ + o*B_ + b] = eps_u[(size_t)b*(T_*2) + t*2 + o];
}

// M[768][E] = con_wih[:,512:576] @ fac_w ; Wfb[768] = con_wih[:,512:576] @ fac_b
__global__ void k_composite(const float* __restrict__ conwih, const float* __restrict__ facw,
                            const float* __restrict__ facb, float* __restrict__ M,
                            float* __restrict__ Wfb) {
  const int idx = blockIdx.x*256 + threadIdx.x;
  const int j = idx >> 8, k = idx & 255;
  float acc = 0.0f;
  for (int ff = 0; ff < F_; ++ff)
    acc += conwih[(size_t)j*576 + 512 + ff] * facw[(size_t)ff*E_ + k];
  M[(size_t)j*E_ + k] = acc;
  if (k == 0) {
    float s = 0.0f;
    for (int ff = 0; ff < F_; ++ff) s += conwih[(size_t)j*576 + 512 + ff] * facb[ff];
    Wfb[j] = s;
  }
}

// ------------------------- encoder -----------------------------------------

struct EncArgs {
  const float* xT;             // [T][DIN][B]
  const float* wih[4];
  const float* whh[4];
  const float* bih[4];
  const float* bhh[4];
  float* hT;                   // [4][2][E][B]
  __hip_bfloat16* efS;         // [T][E][B]
  __hip_bfloat16* ebS;
  int* ctl;
};

__global__ __launch_bounds__(256, 1) void k_encoder(EncArgs a) {
  __shared__ int s_sync[2];    // [0]=go, [1]=alive
  volatile int* s_go = &s_sync[0];
  volatile int* s_alive = &s_sync[1];
  const int chain = blockIdx.x >> 6;
  const int rnk   = blockIdx.x & 63;
  const int jjg   = rnk >> 1;
  const int bg    = rnk & 1;
  const int lane  = threadIdx.x & 63;
  const int w     = threadIdx.x >> 6;
  const int b     = bg*64 + lane;
  if (threadIdx.x == 0) { s_sync[0] = 1; s_sync[1] = 1; }
  __syncthreads();

  const float* wih = a.wih[chain];
  const float* whh = a.whh[chain];
  const float* bih = a.bih[chain];
  const float* bhh = a.bhh[chain];
  float* hTc = a.hT + (size_t)chain*2*GEB;
  const bool bwd = (chain >= 2);
  __hip_bfloat16* st = (chain == 1) ? a.efS : (chain == 3 ? a.ebS : nullptr);
  int* ctl = a.ctl;

  int j0 = jjg*8 + 2*w;
  j0 = __builtin_amdgcn_readfirstlane(j0);
  const int j1 = j0 + 1;

  const float brz0 = bih[j0] + bhh[j0];
  const float brz1 = bih[j1] + bhh[j1];
  const float bz0  = bih[E_+j0] + bhh[E_+j0];
  const float bz1  = bih[E_+j1] + bhh[E_+j1];
  const float bni0 = bih[2*E_+j0], bni1 = bih[2*E_+j1];
  const float bnh0 = bhh[2*E_+j0], bnh1 = bhh[2*E_+j1];

  const float4* wr0x = (const float4*)(wih + (size_t)j0*DIN_);
  const float4* wz0x = (const float4*)(wih + (size_t)(E_+j0)*DIN_);
  const float4* wn0x = (const float4*)(wih + (size_t)(2*E_+j0)*DIN_);
  const float4* wr1x = (const float4*)(wih + (size_t)j1*DIN_);
  const float4* wz1x = (const float4*)(wih + (size_t)(E_+j1)*DIN_);
  const float4* wn1x = (const float4*)(wih + (size_t)(2*E_+j1)*DIN_);
  const float4* wr0h = (const float4*)(whh + (size_t)j0*E_);
  const float4* wz0h = (const float4*)(whh + (size_t)(E_+j0)*E_);
  const float4* wn0h = (const float4*)(whh + (size_t)(2*E_+j0)*E_);
  const float4* wr1h = (const float4*)(whh + (size_t)j1*E_);
  const float4* wz1h = (const float4*)(whh + (size_t)(E_+j1)*E_);
  const float4* wn1h = (const float4*)(whh + (size_t)(2*E_+j1)*E_);

  int p = 0;
  for (int t = 0; t < T_; ++t) {
    const int tt = bwd ? (T_-1-t) : t;
    const float* xp = a.xT + (size_t)tt*DIN_*B_ + b;
    const float* hp = hTc + (size_t)p*GEB + b;
    float ar0=0,az0=0,an0=0,ah0=0, ar1=0,az1=0,an1=0,ah1=0;
    for (int k4 = 0; k4 < 16; ++k4) {
      const float x0 = xp[(4*k4+0)*B_], x1 = xp[(4*k4+1)*B_];
      const float x2 = xp[(4*k4+2)*B_], x3 = xp[(4*k4+3)*B_];
      float4 v;
      v = wr0x[k4]; ar0 += v.x*x0 + v.y*x1 + v.z*x2 + v.w*x3;
      v = wz0x[k4]; az0 += v.x*x0 + v.y*x1 + v.z*x2 + v.w*x3;
      v = wn0x[k4]; an0 += v.x*x0 + v.y*x1 + v.z*x2 + v.w*x3;
      v = wr1x[k4]; ar1 += v.x*x0 + v.y*x1 + v.z*x2 + v.w*x3;
      v = wz1x[k4]; az1 += v.x*x0 + v.y*x1 + v.z*x2 + v.w*x3;
      v = wn1x[k4]; an1 += v.x*x0 + v.y*x1 + v.z*x2 + v.w*x3;
    }
    for (int k4 = 0; k4 < 64; ++k4) {
      const float h0 = ldc_f32(hp + (4*k4+0)*B_);
      const float h1 = ldc_f32(hp + (4*k4+1)*B_);
      const float h2 = ldc_f32(hp + (4*k4+2)*B_);
      const float h3 = ldc_f32(hp + (4*k4+3)*B_);
      float4 v;
      v = wr0h[k4]; ar0 += v.x*h0 + v.y*h1 + v.z*h2 + v.w*h3;
      v = wz0h[k4]; az0 += v.x*h0 + v.y*h1 + v.z*h2 + v.w*h3;
      v = wn0h[k4]; ah0 += v.x*h0 + v.y*h1 + v.z*h2 + v.w*h3;
      v = wr1h[k4]; ar1 += v.x*h0 + v.y*h1 + v.z*h2 + v.w*h3;
      v = wz1h[k4]; az1 += v.x*h0 + v.y*h1 + v.z*h2 + v.w*h3;
      v = wn1h[k4]; ah1 += v.x*h0 + v.y*h1 + v.z*h2 + v.w*h3;
    }
    const float hprev0 = ldc_f32(hp + j0*B_);
    const float hprev1 = ldc_f32(hp + j1*B_);
    const float r0 = sigm_(ar0 + brz0);
    const float z0 = sigm_(az0 + bz0);
    const float n0 = tanhf(an0 + bni0 + r0*(ah0 + bnh0));
    const float h0n = fminf((1.0f - z0)*n0 + z0*hprev0, CLIPV);
    const float r1 = sigm_(ar1 + brz1);
    const float z1 = sigm_(az1 + bz1);
    const float n1 = tanhf(an1 + bni1 + r1*(ah1 + bnh1));
    const float h1n = fminf((1.0f - z1)*n1 + z1*hprev1, CLIPV);
    float* hq = hTc + (size_t)(p^1)*GEB;
    stc_f32(hq + j0*B_ + b, h0n);
    stc_f32(hq + j1*B_ + b, h1n);
    if (st) {
      st[(size_t)tt*GEB + (size_t)j0*B_ + b] = __float2bfloat16(h0n);
      st[(size_t)tt*GEB + (size_t)j1*B_ + b] = __float2bfloat16(h1n);
    }
    postS_(ctl, ES_LINE(chain, rnk), t+1);
    {
      const int tgt = t + 1;
      waitT_([&]() -> int {
        const int v = ld_line(ctl + (ES_LINE(chain, 0) + (int)(threadIdx.x & 63))*16) - tgt;
        return wave_min_ok(v);
      }, s_go, s_alive);
    }
    p ^= 1;
  }
}

// ------------------------- g0 sample ----------------------------------------
// Writes g0 into PP slot 0 .x (c stays 0 from memset).

__global__ void k_g0(const float* __restrict__ hT, const float* __restrict__ g0mw,
                     const float* __restrict__ g0mb, const float* __restrict__ g0vw,
                     const float* __restrict__ g0vb, const float* __restrict__ eps_g0,
                     float* __restrict__ ppx) {
  const int b = threadIdx.x & 127;
  const int half = threadIdx.x >> 7;
  const int kout = blockIdx.x*2 + half;
  const float* hf = hT;                 // chain0 (egf), buffer 0
  const float* hb = hT + 4*GEB;         // chain2 (egb), buffer 0
  const float* mrow = g0mw + (size_t)kout*512;
  const float* vrow = g0vw + (size_t)kout*512;
  float dm = 0.0f, dv = 0.0f;
  for (int k = 0; k < E_; ++k) {
    const float hv = hf[k*B_ + b];
    dm += mrow[k]*hv; dv += vrow[k]*hv;
  }
  for (int k = 0; k < E_; ++k) {
    const float hv = hb[k*B_ + b];
    dm += mrow[256+k]*hv; dv += vrow[256+k]*hv;
  }
  const float lv = fmaxf(dv + g0vb[kout], LVMIN_);
  const float g = eps_g0[(size_t)b*E_ + kout]*expf(0.5f*lv) + dm + g0mb[kout];
  ppx[((size_t)kout*B_ + b)*2] = g;     // slot 0 .x
}

// ------------------------- generator (3 roles) -------------------------------

struct GenAll {
  const float* M; const float* conwhh; const float* genwhh;
  const float* conbih; const float* conbhh; const float* Wfb;
  const float* genwih; const float* genbih; const float* genbhh;
  const float* umw; const float* umb; const float* uvw; const float* uvb;
  const float* epsT;          // [T][2][B]
  const float* conwih;        // [768][576]
  const __hip_bfloat16* efS;  // [T][E][B]
  const __hip_bfloat16* ebS;
  uint_t* ge;                 // ring [128][768][B] bf16, u32 = 2 packed b's
  ull_t* PP;                  // ring [4][E][B] packed (g,c) f32 pairs
  const float* facw; const float* facb;
  const float* f1w; const float* f1b;
  const float* clw; const float* clb;
  float* out;                 // [B][T][DOUT]
  int* ctl;
};

__global__ __launch_bounds__(256, 1) void k_generator(GenAll a) {
  __shared__ __align__(16) unsigned char s_raw[60416];
  const int lane = threadIdx.x & 63;
  const int w = threadIdx.x >> 6;
  int* ctl = a.ctl;

  if (blockIdx.x < 128) {
    // ======================= consumer =======================
    float* s_up = (float*)s_raw;                       // [4][256] 4096 B
    volatile int* s_go    = (volatile int*)(s_raw + 4096);
    volatile int* s_alive = (volatile int*)(s_raw + 4100);
    const int jjgq = blockIdx.x >> 1;
    const int g = blockIdx.x & 1;
    const int b = g*64 + lane;
    if (threadIdx.x == 0) { *s_go = 1; *s_alive = 1; }
    __syncthreads();

    int j = jjgq*4 + w;
    j = __builtin_amdgcn_readfirstlane(j);

    const float4* Mr  = (const float4*)(a.M + (size_t)j*E_);
    const float4* Mz  = (const float4*)(a.M + (size_t)(E_+j)*E_);
    const float4* Mn  = (const float4*)(a.M + (size_t)(2*E_+j)*E_);
    const float4* Whr = (const float4*)(a.conwhh + (size_t)j*E_);
    const float4* Whz = (const float4*)(a.conwhh + (size_t)(E_+j)*E_);
    const float4* Whn = (const float4*)(a.conwhh + (size_t)(2*E_+j)*E_);
    const float4* Gwr = (const float4*)(a.genwhh + (size_t)j*E_);
    const float4* Gwz = (const float4*)(a.genwhh + (size_t)(E_+j)*E_);
    const float4* Gwn = (const float4*)(a.genwhh + (size_t)(2*E_+j)*E_);
    const float* uw0 = a.umw;
    const float* uw1 = a.umw + E_;
    const float* uw2 = a.uvw;
    const float* uw3 = a.uvw + E_;

    const float brz_c = a.conbih[j] + a.conbhh[j] + a.Wfb[j];
    const float bz_c  = a.conbih[E_+j] + a.conbhh[E_+j] + a.Wfb[E_+j];
    const float bni_c = a.conbih[2*E_+j] + a.Wfb[2*E_+j];
    const float bnh_c = a.conbhh[2*E_+j];
    const float gur0 = a.genwih[j*2],        gur1 = a.genwih[j*2+1];
    const float guz0 = a.genwih[(E_+j)*2],   guz1 = a.genwih[(E_+j)*2+1];
    const float gun0 = a.genwih[(2*E_+j)*2], gun1 = a.genwih[(2*E_+j)*2+1];
    const float brz_g = a.genbih[j] + a.genbhh[j];
    const float bz_g  = a.genbih[E_+j] + a.genbhh[E_+j];
    const float bni_g = a.genbih[2*E_+j];
    const float bnh_g = a.genbhh[2*E_+j];
    const float umb0 = a.umb[0], umb1 = a.umb[1];
    const float uvb0 = a.uvb[0], uvb1 = a.uvb[1];

    for (int t = 0; t < T_; ++t) {
      // start: g_{t-1} complete (own half) AND MLP finished step t-4
      {
        const int t1 = 2*t, t2 = t - 3;
        waitT_([&]() -> int {
          int v = ld_line(ctl + (CS_LINE(g, 0) + lane)*16) - t1;
          if (lane < 16)
            v = min(v, ld_line(ctl + (MS_LINE(g, 0) + lane)*16) - t2);
          return wave_min_ok(v);
        }, s_go, s_alive);
      }
      const ull_t* ppb = a.PP + (size_t)(t & 3)*GEB + b;
      ull_t* ppn = a.PP + (size_t)((t+1) & 3)*GEB;
      const ull_t pv = ldc_u64(ppb + (size_t)j*B_);
      const float gprev = __uint_as_float((unsigned)pv);
      const float cprev = __uint_as_float((unsigned)(pv >> 32));
      float ar=0,az=0,an=0,ah=0,gr=0,gz=0,gh=0;
      for (int k4 = 0; k4 < 64; ++k4) {
        const ull_t v0 = ldc_u64(ppb + (4*k4+0)*B_);
        const ull_t v1 = ldc_u64(ppb + (4*k4+1)*B_);
        const ull_t v2 = ldc_u64(ppb + (4*k4+2)*B_);
        const ull_t v3 = ldc_u64(ppb + (4*k4+3)*B_);
        const float g0 = __uint_as_float((unsigned)v0), c0 = __uint_as_float((unsigned)(v0>>32));
        const float g1 = __uint_as_float((unsigned)v1), c1 = __uint_as_float((unsigned)(v1>>32));
        const float g2 = __uint_as_float((unsigned)v2), c2 = __uint_as_float((unsigned)(v2>>32));
        const float g3 = __uint_as_float((unsigned)v3), c3 = __uint_as_float((unsigned)(v3>>32));
        float4 v;
        v = Mr[k4];  ar += v.x*g0 + v.y*g1 + v.z*g2 + v.w*g3;
        v = Mz[k4];  az += v.x*g0 + v.y*g1 + v.z*g2 + v.w*g3;
        v = Mn[k4];  an += v.x*g0 + v.y*g1 + v.z*g2 + v.w*g3;
        v = Gwr[k4]; gr += v.x*g0 + v.y*g1 + v.z*g2 + v.w*g3;
        v = Gwz[k4]; gz += v.x*g0 + v.y*g1 + v.z*g2 + v.w*g3;
        v = Gwn[k4]; gh += v.x*g0 + v.y*g1 + v.z*g2 + v.w*g3;
        v = Whr[k4]; ar += v.x*c0 + v.y*c1 + v.z*c2 + v.w*c3;
        v = Whz[k4]; az += v.x*c0 + v.y*c1 + v.z*c2 + v.w*c3;
        v = Whn[k4]; ah += v.x*c0 + v.y*c1 + v.z*c2 + v.w*c3;
      }
      // ge[t] flag, then its 3 contributions
      {
        const int tgt = 48*((t >> 7) + 1);
        int* fl = ctl + LF_LINE(t & 127)*16;
        waitT_([&]() -> int { return ld_line(fl) >= tgt; }, s_go, s_alive);
      }
      {
        const uint_t* geb = a.ge + ((size_t)(t & 127)*(768*B_) >> 1) + (b >> 1);
        const uint_t u0 = ldc_u32(geb + j*(B_/2));
        const uint_t u1 = ldc_u32(geb + (E_+j)*(B_/2));
        const uint_t u2 = ldc_u32(geb + (2*E_+j)*(B_/2));
        const int hi = b & 1;
        ar += bfu_((ushort_t)(hi ? (u0 >> 16) : u0));
        az += bfu_((ushort_t)(hi ? (u1 >> 16) : u1));
        an += bfu_((ushort_t)(hi ? (u2 >> 16) : u2));
      }
      const float r = sigm_(ar + brz_c);
      const float z = sigm_(az + bz_c);
      const float n = tanhf(an + bni_c + r*(ah + bnh_c));
      const float cn = fminf((1.0f - z)*n + z*cprev, CLIPV);
      stc_f32((float*)(ppn + (size_t)j*B_ + b) + 1, cn);    // .y = c
      postS_(ctl, CS_LINE(g, jjgq), 2*t + 1);
      {
        const int tgt = 2*t + 1;
        waitT_([&]() -> int {
          const int v = ld_line(ctl + (CS_LINE(g, 0) + lane)*16) - tgt;
          return wave_min_ok(v);
        }, s_go, s_alive);
      }

      // ---- u partials over this wave's k-quarter of fresh c ----
      {
        const float* cq = (const float*)(ppn + b);
        float p0=0,p1=0,p2=0,p3=0;
        for (int kk = 0; kk < 64; ++kk) {
          const int k = w*64 + kk;
          const float cv = ldc_f32(cq + (size_t)k*B_*2 + 1);
          p0 += uw0[k]*cv; p1 += uw1[k]*cv; p2 += uw2[k]*cv; p3 += uw3[k]*cv;
        }
        s_up[0*256 + threadIdx.x] = p0;
        s_up[1*256 + threadIdx.x] = p1;
        s_up[2*256 + threadIdx.x] = p2;
        s_up[3*256 + threadIdx.x] = p3;
      }
      __syncthreads();
      const float m0 = s_up[lane] + s_up[64+lane] + s_up[128+lane] + s_up[192+lane] + umb0;
      const float m1 = s_up[256+lane] + s_up[320+lane] + s_up[384+lane] + s_up[448+lane] + umb1;
      const float lv0 = fmaxf(s_up[512+lane] + s_up[576+lane] + s_up[640+lane] + s_up[704+lane] + uvb0, LVMIN_);
      const float lv1 = fmaxf(s_up[768+lane] + s_up[832+lane] + s_up[896+lane] + s_up[960+lane] + uvb1, LVMIN_);
      __syncthreads();
      const float eps0 = a.epsT[(size_t)t*256 + b];
      const float eps1 = a.epsT[(size_t)t*256 + 128 + b];
      const float u0 = eps0*expf(0.5f*lv0) + m0;
      const float u1 = eps1*expf(0.5f*lv1) + m1;

      const float rg = sigm_(gr + gur0*u0 + gur1*u1 + brz_g);
      const float zg = sigm_(gz + guz0*u0 + guz1*u1 + bz_g);
      const float ng = tanhf(gun0*u0 + gun1*u1 + bni_g + rg*(gh + bnh_g));
      const float gn = fminf((1.0f - zg)*ng + zg*gprev, CLIPV);
      stc_f32((float*)(ppn + (size_t)j*B_ + b), gn);        // .x = g
      postS_(ctl, CS_LINE(g, jjgq), 2*t + 2);
    }
  } else if (blockIdx.x < 224) {
    // ======================= producer =======================
    volatile int* s_go    = (volatile int*)s_raw;
    volatile int* s_alive = (volatile int*)(s_raw + 4);
    const int pid = blockIdx.x - 128;
    const int tile = pid % 48, phase = pid / 48;
    const int r0 = tile*16;
    if (threadIdx.x == 0) { *s_go = 1; *s_alive = 1; }
    __syncthreads();
    const int rl0 = w*4;
    const float* rp0 = a.conwih + (size_t)(r0 + rl0 + 0)*576;
    const float* rp1 = a.conwih + (size_t)(r0 + rl0 + 1)*576;
    const float* rp2 = a.conwih + (size_t)(r0 + rl0 + 2)*576;
    const float* rp3 = a.conwih + (size_t)(r0 + rl0 + 3)*576;
    for (int t = phase; t < T_; t += 2) {
      if (t >= 128) {   // ring guard: both halves past step t-127's c-post
        const int tgt = 2*(t - 127) + 1;
        waitT_([&]() -> int {
          const int v0 = ld_line(ctl + (CS_LINE(0, 0) + lane)*16);
          const int v1 = ld_line(ctl + (CS_LINE(1, 0) + lane)*16);
          return wave_min_ok(min(v0, v1) - tgt);
        }, s_go, s_alive);
      }
      float a0l=0,a0h=0,a1l=0,a1h=0,a2l=0,a2h=0,a3l=0,a3h=0;
      const uint_t* efp = (const uint_t*)a.efS + (((size_t)t*GEB) >> 1) + lane;
      const uint_t* ebp = (const uint_t*)a.ebS + (((size_t)t*GEB) >> 1) + lane;
      for (int k4 = 0; k4 < 64; ++k4) {
        const float4 w0 = *(const float4*)(rp0 + 4*k4);
        const float4 w1 = *(const float4*)(rp1 + 4*k4);
        const float4 w2 = *(const float4*)(rp2 + 4*k4);
        const float4 w3 = *(const float4*)(rp3 + 4*k4);
        #pragma unroll
        for (int i = 0; i < 4; ++i) {
          const uint_t u = efp[(4*k4+i)*(B_/2)];
          const float el = bfu_((ushort_t)u), eh = bfu_((ushort_t)(u >> 16));
          const float wv0 = (&w0.x)[i], wv1 = (&w1.x)[i], wv2 = (&w2.x)[i], wv3 = (&w3.x)[i];
          a0l += wv0*el; a0h += wv0*eh; a1l += wv1*el; a1h += wv1*eh;
          a2l += wv2*el; a2h += wv2*eh; a3l += wv3*el; a3h += wv3*eh;
        }
      }
      for (int k4 = 0; k4 < 64; ++k4) {
        const float4 w0 = *(const float4*)(rp0 + 256 + 4*k4);
        const float4 w1 = *(const float4*)(rp1 + 256 + 4*k4);
        const float4 w2 = *(const float4*)(rp2 + 256 + 4*k4);
        const float4 w3 = *(const float4*)(rp3 + 256 + 4*k4);
        #pragma unroll
        for (int i = 0; i < 4; ++i) {
          const uint_t u = ebp[(4*k4+i)*(B_/2)];
          const float el = bfu_((ushort_t)u), eh = bfu_((ushort_t)(u >> 16));
          const float wv0 = (&w0.x)[i], wv1 = (&w1.x)[i], wv2 = (&w2.x)[i], wv3 = (&w3.x)[i];
          a0l += wv0*el; a0h += wv0*eh; a1l += wv1*el; a1h += wv1*eh;
          a2l += wv2*el; a2h += wv2*eh; a3l += wv3*el; a3h += wv3*eh;
        }
      }
      uint_t* gesl = a.ge + (((size_t)(t & 127)*(768*B_)) >> 1) + (size_t)(r0 + rl0)*(B_/2) + lane;
      stc_u32(gesl + 0*(B_/2), ((uint_t)bfbits_(a0h) << 16) | bfbits_(a0l));
      stc_u32(gesl + 1*(B_/2), ((uint_t)bfbits_(a1h) << 16) | bfbits_(a1l));
      stc_u32(gesl + 2*(B_/2), ((uint_t)bfbits_(a2h) << 16) | bfbits_(a2l));
      stc_u32(gesl + 3*(B_/2), ((uint_t)bfbits_(a3h) << 16) | bfbits_(a3l));
      postF_(ctl, LF_LINE(t & 127));
    }
  } else {
    // ======================= output MLP (lag-tolerant) =======================
    __hip_bfloat16* s_fw  = (__hip_bfloat16*)s_raw;              // [256][64] 32768
    __hip_bfloat16* s_f1T = (__hip_bfloat16*)(s_raw + 32768);    // [64][80] 10240
    __hip_bfloat16* s_clT = (__hip_bfloat16*)(s_raw + 43008);    // [80][64] 10240
    float* s_g  = (float*)(s_raw + 53248);                       // [4][256] 4096
    float* s_f  = (float*)(s_raw + 57344);                       // [4][64]  1024
    float* s_h1 = (float*)(s_raw + 58368);                       // [4][80]  1280
    volatile int* s_go    = (volatile int*)(s_raw + 59648);
    volatile int* s_alive = (volatile int*)(s_raw + 59652);
    if (threadIdx.x == 0) { *s_go = 1; *s_alive = 1; }
    for (int idx = threadIdx.x; idx < 16384; idx += 256) {
      const int k = idx >> 6, fd = idx & 63;
      s_fw[idx] = __float2bfloat16(a.facw[(size_t)fd*E_ + k]);
    }
    for (int idx = threadIdx.x; idx < 5120; idx += 256) {
      const int kf = idx / H1_, hd = idx % H1_;
      s_f1T[idx] = __float2bfloat16(a.f1w[(size_t)hd*64 + kf]);
    }
    for (int idx = threadIdx.x; idx < 5120; idx += 256) {
      const int kh = idx >> 6, od = idx & 63;
      s_clT[idx] = __float2bfloat16(a.clw[(size_t)od*H1_ + kh]);
    }
    __syncthreads();
    const int oid = blockIdx.x - 224;
    const int g = oid & 1;
    const int idxm = oid >> 1;           // 0..15
    int bw = g*64 + idxm*4 + w;
    bw = __builtin_amdgcn_readfirstlane(bw);
    const float facb_l = a.facb[lane];
    const float f1b_a  = a.f1b[lane];
    const float f1b_b  = (lane < 16) ? a.f1b[64 + lane] : 0.0f;
    const float clb_l  = a.clb[lane];
    for (int m = 0; m < T_; ++m) {
      {
        const int tgt = 2*m + 2;       // g_m posted by own half
        waitT_([&]() -> int {
          const int v = ld_line(ctl + (CS_LINE(g, 0) + lane)*16) - tgt;
          return wave_min_ok(v);
        }, s_go, s_alive);
      }
      // snapshot g_m from PP slot (m+1)&3, THEN release consumers
      {
        const float* ppx = (const float*)(a.PP + (size_t)((m+1) & 3)*GEB);
        #pragma unroll
        for (int i = 0; i < 4; ++i) {
          const int k = lane + 64*i;
          s_g[w*256 + k] = ldc_f32(ppx + ((size_t)k*B_ + bw)*2);
        }
      }
      postS_(ctl, MS_LINE(g, idxm), m + 1);
      float f = facb_l;
      for (int k = 0; k < 256; ++k)
        f += __bfloat162float(s_fw[k*64 + lane]) * s_g[w*256 + k];
      s_f[w*64 + lane] = f;
      __syncthreads();
      float h1a = f1b_a, h1b = f1b_b;
      for (int kf = 0; kf < 64; ++kf) {
        const float fv = s_f[w*64 + kf];
        h1a += __bfloat162float(s_f1T[kf*H1_ + lane]) * fv;
        if (lane < 16) h1b += __bfloat162float(s_f1T[kf*H1_ + 64 + lane]) * fv;
      }
      s_h1[w*H1_ + lane] = fmaxf(h1a, 0.0f);
      if (lane < 16) s_h1[w*H1_ + 64 + lane] = fmaxf(h1b, 0.0f);
      __syncthreads();
      float o = clb_l;
      for (int kh = 0; kh < H1_; ++kh)
        o += __bfloat162float(s_clT[kh*64 + lane]) * s_h1[w*H1_ + kh];
      a.out[((size_t)bw*T_ + m)*DOUT_ + lane] = o;
      __syncthreads();
    }
  }
}

// ------------------------- host launcher ------------------------------------

extern "C" void kernel_launch(void* const* d_in, const int* in_sizes, int n_in,
                              void* d_out, int out_size, void* d_ws, size_t ws_size,
                              hipStream_t stream) {
  const float* x      = (const float*)d_in[0];
  const float* eps_g0 = (const float*)d_in[1];
  const float* eps_u  = (const float*)d_in[2];
  const float* egf_wih = (const float*)d_in[3],  *egf_whh = (const float*)d_in[4];
  const float* egf_bih = (const float*)d_in[5],  *egf_bhh = (const float*)d_in[6];
  const float* egb_wih = (const float*)d_in[7],  *egb_whh = (const float*)d_in[8];
  const float* egb_bih = (const float*)d_in[9],  *egb_bhh = (const float*)d_in[10];
  const float* ecf_wih = (const float*)d_in[11], *ecf_whh = (const float*)d_in[12];
  const float* ecf_bih = (const float*)d_in[13], *ecf_bhh = (const float*)d_in[14];
  const float* ecb_wih = (const float*)d_in[15], *ecb_whh = (const float*)d_in[16];
  const float* ecb_bih = (const float*)d_in[17], *ecb_bhh = (const float*)d_in[18];
  const float* con_wih = (const float*)d_in[19], *con_whh = (const float*)d_in[20];
  const float* con_bih = (const float*)d_in[21], *con_bhh = (const float*)d_in[22];
  const float* gen_wih = (const float*)d_in[23], *gen_whh = (const float*)d_in[24];
  const float* gen_bih = (const float*)d_in[25], *gen_bhh = (const float*)d_in[26];
  const float* g0m_w = (const float*)d_in[27], *g0m_b = (const float*)d_in[28];
  const float* g0v_w = (const float*)d_in[29], *g0v_b = (const float*)d_in[30];
  const float* um_w = (const float*)d_in[31], *um_b = (const float*)d_in[32];
  const float* uv_w = (const float*)d_in[33], *uv_b = (const float*)d_in[34];
  const float* fac_w = (const float*)d_in[35], *fac_b = (const float*)d_in[36];
  const float* f1_w = (const float*)d_in[37], *f1_b = (const float*)d_in[38];
  const float* cl_w = (const float*)d_in[39], *cl_b = (const float*)d_in[40];
  float* out = (float*)d_out;
  (void)ws_size; (void)in_sizes; (void)n_in; (void)out_size;

  // Workspace layout — total 167,262,208 B <= proven 167,297,024 B.
  // xT region [0,32.77MB) is dead after the encoder; ge ring uses its first
  // 25.17MB and the PP ring (depth 4, 1MB) its tail.
  char* ws = (char*)d_ws;
  const size_t o_xT   = 0;             // f32 [T][DIN][B]        32,768,000
  const size_t o_ge   = 0;             // bf16 [128][768][B]     25,165,824 (alias)
  const size_t o_PP   = 25165824ul;    // ull [4][E][B]           1,048,576 (alias)
  const size_t o_efS  = 32768000ul;    // bf16 [T][E][B]         65,536,000
  const size_t o_ebS  = 98304000ul;    //                        65,536,000
  const size_t o_epsT = 163840000ul;   // f32 [T][2][B]           1,024,000
  const size_t o_M    = 164864000ul;   // f32 [768][E]              786,432
  const size_t o_Wfb  = 165650432ul;   // f32 [768]                   4,096
  const size_t o_hT   = 165654528ul;   // f32 [4][2][E][B]        1,048,576
  const size_t o_ctl  = 167227392ul;   // 544 control lines          34,816
  const size_t o_end  = 167262208ul;

  float* xT = (float*)(ws + o_xT);
  uint_t* ge = (uint_t*)(ws + o_ge);
  ull_t* PP = (ull_t*)(ws + o_PP);
  __hip_bfloat16* efS = (__hip_bfloat16*)(ws + o_efS);
  __hip_bfloat16* ebS = (__hip_bfloat16*)(ws + o_ebS);
  float* epsT = (float*)(ws + o_epsT);
  float* M = (float*)(ws + o_M);
  float* Wfb = (float*)(ws + o_Wfb);
  float* hT = (float*)(ws + o_hT);
  int* ctl = (int*)(ws + o_ctl);

  // zero hT + (dead gap) + control lines
  hipMemsetAsync(ws + o_hT, 0, o_end - o_hT, stream);

  k_transpose_x<<<dim3(T_, 2), 256, 0, stream>>>(x, xT);
  k_transpose_eps<<<T_, 256, 0, stream>>>(eps_u, epsT);
  k_composite<<<768, 256, 0, stream>>>(con_wih, fac_w, fac_b, M, Wfb);

  EncArgs ea;
  ea.xT = xT;
  ea.wih[0] = egf_wih; ea.whh[0] = egf_whh; ea.bih[0] = egf_bih; ea.bhh[0] = egf_bhh;
  ea.wih[1] = ecf_wih; ea.whh[1] = ecf_whh; ea.bih[1] = ecf_bih; ea.bhh[1] = ecf_bhh;
  ea.wih[2] = egb_wih; ea.whh[2] = egb_whh; ea.bih[2] = egb_bih; ea.bhh[2] = egb_bhh;
  ea.wih[3] = ecb_wih; ea.whh[3] = ecb_whh; ea.bih[3] = ecb_bih; ea.bhh[3] = ecb_bhh;
  ea.hT = hT; ea.efS = efS; ea.ebS = ebS; ea.ctl = ctl;
  k_encoder<<<256, 256, 0, stream>>>(ea);

  // PP ring lives inside the (now dead) xT region: zero it AFTER the encoder.
  hipMemsetAsync(ws + o_PP, 0, 1048576ul, stream);

  k_g0<<<128, 256, 0, stream>>>(hT, g0m_w, g0m_b, g0v_w, g0v_b, eps_g0, (float*)PP);

  GenAll ga;
  ga.M = M; ga.conwhh = con_whh; ga.genwhh = gen_whh;
  ga.conbih = con_bih; ga.conbhh = con_bhh; ga.Wfb = Wfb;
  ga.genwih = gen_wih; ga.genbih = gen_bih; ga.genbhh = gen_bhh;
  ga.umw = um_w; ga.umb = um_b; ga.uvw = uv_w; ga.uvb = uv_b;
  ga.epsT = epsT; ga.conwih = con_wih;
  ga.efS = efS; ga.ebS = ebS; ga.ge = ge; ga.PP = PP;
  ga.facw = fac_w; ga.facb = fac_b;
  ga.f1w = f1_w; ga.f1b = f1_b; ga.clw = cl_w; ga.clb = cl_b;
  ga.out = out;
  ga.ctl = ctl;
  k_generator<<<256, 256, 0, stream>>>(ga);
}